// Round 9
// baseline (203.274 us; speedup 1.0000x reference)
//
#include <hip/hip_runtime.h>
#include <math.h>

#define HH 384
#define WW 384
#define HWSZ (HH*WW)
#define NPLANES 256
#define EPSBN 1e-5f

#define THREADS 768
#define CHUNK 192
#define NBLK (NPLANES*2)       // 512 blocks, one per half-plane
#define RING 46                // ring slots (live span 42)
#define PADW 420               // 17 left halo + 384 + 18 right halo + pad
#define STEPS (CHUNK/4)        // 48 (4 rows per step)
#define PRO_ROWS 38            // prologue ordinals 0..37 (rows h0-17..h0+20)
#define MAX_ORD 225            // last ordinal = 191+17+17

typedef float f2v __attribute__((ext_vector_type(2)));

__device__ __forceinline__ int wrap384(int x) {
  return x < 0 ? x + 384 : (x >= 384 ? x - 384 : x);
}

// XCD-chunked bijective swizzle for 512 blocks; both chunks of a plane same XCD
__device__ __forceinline__ int vswz() {
  const int b = blockIdx.x;
  return (b & 7) * (NBLK / 8) + (b >> 3);
}

// MODE 0: BN partial stats.  MODE 1: affine combine + NT store.
template<int MODE>
__global__ __launch_bounds__(THREADS, 6)
void ring_kernel(const float* __restrict__ cen,
                 const float* __restrict__ coef,
                 float* __restrict__ partials,
                 float* __restrict__ out)
{
  __shared__ float ring[RING * PADW];   // 77,280 B
  __shared__ float red[12][4];

  const int v     = vswz();
  const int plane = v >> 1;
  const int h0    = (v & 1) * CHUNK;
  const int t     = threadIdx.x;
  const float* pp = cen + (size_t)plane * HWSZ;

  // ---- prologue: rows h0-17 .. h0+20 (ordinals 0..37), halo-padded ----
  for (int W = t; W < PRO_ROWS * PADW; W += THREADS) {
    int o  = W / PADW;
    int c  = W - o * PADW;
    int gr = wrap384(h0 + o - 17);
    int gc = c - 17; gc = gc < 0 ? gc + 384 : (gc >= 384 ? gc - 384 : gc);
    ring[o * PADW + c] = pp[gr * WW + gc];
  }

  const int rr = t / 192;               // row within 4-row group
  const int w0 = 2 * (t - rr * 192);    // even column, this thread does w0,w0+1

  float CA = 0.f, CB = 0.f, CC = 0.f;
  if (MODE == 1) {
    CA = coef[plane*4+0]; CB = coef[plane*4+1]; CC = coef[plane*4+2];
  }
  float s13 = 0.f, q13 = 0.f, s17 = 0.f, q17 = 0.f;

  for (int s = 0; s < STEPS; ++s) {
    // ---- prefetch rows (ordinals 38+4s .. 41+4s), 21 rows ahead of use ----
    const int obase = PRO_ROWS + 4*s;
    #pragma unroll
    for (int k = 0; k < 3; ++k) {
      int W = t + k * THREADS;
      if (W < 4 * PADW) {
        int r = W / PADW;
        int c = W - r * PADW;
        int o = obase + r;
        if (o <= MAX_ORD) {
          int gr = wrap384(h0 + o - 17);
          int gc = c - 17; gc = gc < 0 ? gc + 384 : (gc >= 384 ? gc - 384 : gc);
          ring[(o % RING) * PADW + c] = pp[gr * WW + gc];
        }
      }
    }
    __syncthreads();   // single barrier/step: next prefetch hits slots older than any live read

    // ---- compute rows h0+4s+rr (ordinal 17+4s+rr) for 2 adjacent pixels ----
    const int ord = 17 + 4*s + rr;
    const float* Rc   = ring + ((ord)      % RING) * PADW + w0;
    const float* Rm13 = ring + ((ord - 13) % RING) * PADW + w0;
    const float* Rp13 = ring + ((ord + 13) % RING) * PADW + w0;
    const float* Rm17 = ring + ((ord - 17) % RING) * PADW + w0;
    const float* Rp17 = ring + ((ord + 17) % RING) * PADW + w0;
    // offset j maps to column w0-17+j ; needed j: 0,1 / 4,5 / 17,18 / 30,31 / 34,35
    float r0_0 = Rc[0],  r0_1 = Rc[1],  r0_4 = Rc[4],  r0_5 = Rc[5];
    float dA   = Rc[17], dB   = Rc[18];
    float r0_30= Rc[30], r0_31= Rc[31], r0_34= Rc[34], r0_35= Rc[35];
    float m13_4 = Rm13[4],  m13_5 = Rm13[5],  m13_17 = Rm13[17];
    float m13_18= Rm13[18], m13_30= Rm13[30], m13_31 = Rm13[31];
    float p13_4 = Rp13[4],  p13_5 = Rp13[5],  p13_17 = Rp13[17];
    float p13_18= Rp13[18], p13_30= Rp13[30], p13_31 = Rp13[31];
    float m17_0 = Rm17[0],  m17_1 = Rm17[1],  m17_17 = Rm17[17];
    float m17_18= Rm17[18], m17_34= Rm17[34], m17_35 = Rm17[35];
    float p17_0 = Rp17[0],  p17_1 = Rp17[1],  p17_17 = Rp17[17];
    float p17_18= Rp17[18], p17_34= Rp17[34], p17_35 = Rp17[35];

    float a13, a17, b13, b17;
    {
      float s1 = (p13_30 - dA) * (m13_4  - dA);
      float s2 = (p13_17 - dA) * (m13_17 - dA);
      float s3 = (p13_4  - dA) * (m13_30 - dA);
      float s4 = (r0_4   - dA) * (r0_30  - dA);
      a13 = fminf(fminf(s1, s2), fminf(s3, s4));
      float u1 = (p17_34 - dA) * (m17_0  - dA);
      float u2 = (p17_17 - dA) * (m17_17 - dA);
      float u3 = (p17_0  - dA) * (m17_34 - dA);
      float u4 = (r0_0   - dA) * (r0_34  - dA);
      a17 = fminf(fminf(u1, u2), fminf(u3, u4));
    }
    {
      float s1 = (p13_31 - dB) * (m13_5  - dB);
      float s2 = (p13_18 - dB) * (m13_18 - dB);
      float s3 = (p13_5  - dB) * (m13_31 - dB);
      float s4 = (r0_5   - dB) * (r0_31  - dB);
      b13 = fminf(fminf(s1, s2), fminf(s3, s4));
      float u1 = (p17_35 - dB) * (m17_1  - dB);
      float u2 = (p17_18 - dB) * (m17_18 - dB);
      float u3 = (p17_1  - dB) * (m17_35 - dB);
      float u4 = (r0_1   - dB) * (r0_35  - dB);
      b17 = fminf(fminf(u1, u2), fminf(u3, u4));
    }

    if (MODE == 0) {
      s13 += a13 + b13; q13 += a13*a13 + b13*b13;
      s17 += a17 + b17; q17 += a17*a17 + b17*b17;
    } else {
      const int grow = h0 + 4*s + rr;
      f2v o2; o2.x = CA*a13 + CB*a17 + CC; o2.y = CA*b13 + CB*b17 + CC;
      __builtin_nontemporal_store(o2,
          (f2v*)(out + (size_t)plane*HWSZ + (size_t)grow*WW + w0));
    }
  }

  if (MODE == 0) {
    for (int off = 32; off > 0; off >>= 1) {
      s13 += __shfl_down(s13, off);
      q13 += __shfl_down(q13, off);
      s17 += __shfl_down(s17, off);
      q17 += __shfl_down(q17, off);
    }
    const int wid = t >> 6;
    if ((t & 63) == 0) {
      red[wid][0] = s13; red[wid][1] = q13; red[wid][2] = s17; red[wid][3] = q17;
    }
    __syncthreads();
    if (t == 0) {
      float a=0.f, b=0.f, c=0.f, d=0.f;
      for (int i = 0; i < 12; ++i) { a+=red[i][0]; b+=red[i][1]; c+=red[i][2]; d+=red[i][3]; }
      float* q = partials + (size_t)v * 4;
      q[0]=a; q[1]=b; q[2]=c; q[3]=d;
    }
  }
}

// ---- SE MLP helper (256 threads) ----
__device__ void se_mlp(int t, const float* __restrict__ p,
    const float* __restrict__ w1, const float* __restrict__ b1,
    const float* __restrict__ g1, const float* __restrict__ be1,
    const float* __restrict__ w2, const float* __restrict__ b2,
    const float* __restrict__ g2, const float* __restrict__ be2,
    float* y1, float* sc, float* sh, float* wei)
{
  if (t < 128) {
    const int b = t >> 5, o = t & 31;
    float acc = b1[o];
    const float* wr = w1 + o*64;
    const float* pr = p  + b*64;
    #pragma unroll
    for (int c = 0; c < 64; ++c) acc += wr[c]*pr[c];
    y1[t] = acc;
  }
  __syncthreads();
  if (t < 32) {
    float a0=y1[t], a1=y1[32+t], a2=y1[64+t], a3=y1[96+t];
    float m = 0.25f*(a0+a1+a2+a3);
    float q = 0.25f*(a0*a0+a1*a1+a2*a2+a3*a3);
    float vv = q - m*m;
    float s = g1[t]*rsqrtf(vv + EPSBN);
    sc[t] = s; sh[t] = be1[t] - m*s;
  }
  __syncthreads();
  if (t < 128) {
    const int o = t & 31;
    y1[t] = fmaxf(y1[t]*sc[o] + sh[o], 0.0f);
  }
  __syncthreads();
  {
    const int b = t >> 6, o2 = t & 63;
    float acc = b2[o2];
    const float* wr = w2 + o2*32;
    const float* yr = y1 + b*32;
    #pragma unroll
    for (int o = 0; o < 32; ++o) acc += wr[o]*yr[o];
    wei[t] = acc;
  }
  __syncthreads();
  if (t < 64) {
    float a0=wei[t], a1=wei[64+t], a2=wei[128+t], a3=wei[192+t];
    float m = 0.25f*(a0+a1+a2+a3);
    float q = 0.25f*(a0*a0+a1*a1+a2*a2+a3*a3);
    float vv = q - m*m;
    float s = g2[t]*rsqrtf(vv + EPSBN);
    sc[t] = s; sh[t] = be2[t] - m*s;
  }
  __syncthreads();
  {
    const int o2 = t & 63;
    float z = wei[t]*sc[o2] + sh[o2];
    wei[t] = 1.0f/(1.0f + expf(-z));
  }
  __syncthreads();
}

// ---- se: partials -> BN stats -> SE MLPs -> per-plane coefficients ----
__global__ __launch_bounds__(256) void se_kernel(
    const float* __restrict__ partials, int bpp,
    const float* __restrict__ bn1_g, const float* __restrict__ bn1_b,
    const float* __restrict__ bn2_g, const float* __restrict__ bn2_b,
    const float* __restrict__ td_w1, const float* __restrict__ td_b1,
    const float* __restrict__ td_g1, const float* __restrict__ td_be1,
    const float* __restrict__ td_w2, const float* __restrict__ td_b2,
    const float* __restrict__ td_g2, const float* __restrict__ td_be2,
    const float* __restrict__ bu_w1, const float* __restrict__ bu_b1,
    const float* __restrict__ bu_g1, const float* __restrict__ bu_be1,
    const float* __restrict__ bu_w2, const float* __restrict__ bu_b2,
    const float* __restrict__ bu_g2, const float* __restrict__ bu_be2,
    float* __restrict__ coef)
{
  __shared__ float sum13[256], sq13[256], sum17[256], sq17[256];
  __shared__ float scale1[64], shift1[64], scale2[64], shift2[64];
  __shared__ float pm13[256], pm17[256];
  __shared__ float y1[128], sc[64], sh[64];
  __shared__ float tdw[256], buw[256];
  const int t = threadIdx.x;

  {
    float a=0.f,b=0.f,c=0.f,d=0.f;
    for (int kb = 0; kb < bpp; ++kb) {
      const float* q = partials + ((size_t)(t*bpp + kb))*4;
      a += q[0]; b += q[1]; c += q[2]; d += q[3];
    }
    sum13[t]=a; sq13[t]=b; sum17[t]=c; sq17[t]=d;
  }
  __syncthreads();

  if (t < 64) {
    float s=0.f,q=0.f,s2=0.f,q2=0.f;
    for (int b = 0; b < 4; ++b) {
      s  += sum13[b*64+t]; q  += sq13[b*64+t];
      s2 += sum17[b*64+t]; q2 += sq17[b*64+t];
    }
    const float inv = 1.0f/(4.0f*HWSZ);
    float m1 = s*inv,  v1 = q*inv  - m1*m1;
    float c1 = bn1_g[t]*rsqrtf(v1 + EPSBN);
    scale1[t] = c1; shift1[t] = bn1_b[t] - m1*c1;
    float m2 = s2*inv, v2 = q2*inv - m2*m2;
    float c2 = bn2_g[t]*rsqrtf(v2 + EPSBN);
    scale2[t] = c2; shift2[t] = bn2_b[t] - m2*c2;
  }
  __syncthreads();

  {
    const int c = t & 63;
    pm13[t] = (sum13[t]*(1.0f/HWSZ))*scale1[c] + shift1[c];
    pm17[t] = (sum17[t]*(1.0f/HWSZ))*scale2[c] + shift2[c];
  }
  __syncthreads();

  se_mlp(t, pm17, td_w1, td_b1, td_g1, td_be1, td_w2, td_b2, td_g2, td_be2, y1, sc, sh, tdw);
  se_mlp(t, pm13, bu_w1, bu_b1, bu_g1, bu_be1, bu_w2, bu_b2, bu_g2, bu_be2, y1, sc, sh, buw);

  {
    const int c = t & 63;
    float A  = tdw[t]*scale1[c];
    float Bc = buw[t]*scale2[c];
    float Cc = tdw[t]*shift1[c] + buw[t]*shift2[c];
    coef[t*4+0] = A; coef[t*4+1] = Bc; coef[t*4+2] = Cc; coef[t*4+3] = 0.f;
  }
}

extern "C" void kernel_launch(void* const* d_in, const int* in_sizes, int n_in,
                              void* d_out, int out_size, void* d_ws, size_t ws_size,
                              hipStream_t stream) {
  const float* cen = (const float*)d_in[0];
  float* ws = (float*)d_ws;
  float* partials = ws;                        // NBLK*4 floats = 8 KB
  float* coef     = ws + (size_t)NBLK*4;       // 256*4 floats

  ring_kernel<0><<<NBLK, THREADS, 0, stream>>>(cen, nullptr, partials, nullptr);
  se_kernel<<<1, 256, 0, stream>>>(partials, 2,
      (const float*)d_in[1],  (const float*)d_in[2],  (const float*)d_in[3],  (const float*)d_in[4],
      (const float*)d_in[5],  (const float*)d_in[6],  (const float*)d_in[7],  (const float*)d_in[8],
      (const float*)d_in[9],  (const float*)d_in[10], (const float*)d_in[11], (const float*)d_in[12],
      (const float*)d_in[13], (const float*)d_in[14], (const float*)d_in[15], (const float*)d_in[16],
      (const float*)d_in[17], (const float*)d_in[18], (const float*)d_in[19], (const float*)d_in[20],
      coef);
  ring_kernel<1><<<NBLK, THREADS, 0, stream>>>(cen, coef, nullptr, (float*)d_out);
}